// Round 11
// baseline (68.548 us; speedup 1.0000x reference)
//
#include <hip/hip_runtime.h>

#define N 4096
#define F 64
#define H 8
#define W1S (2 * F + 1)   // 129
#define PCH 128           // partial chunks (32 rows each)

typedef float f4 __attribute__((ext_vector_type(4)));

// ---------------------------------------------------------------------------
// Kernel 1: partial column sums of A. grid (4, 128) = 512 blocks, block 256.
// partial[y][col], [128][4096] = 2 MB (L2/LLC-resident for K2).
// ---------------------------------------------------------------------------
__global__ __launch_bounds__(256) void colsum_partial(const float* __restrict__ A,
                                                      float* __restrict__ partial) {
    int c4 = blockIdx.x * 256 + threadIdx.x;
    int r0 = blockIdx.y * 32;
    const float* p = A + (size_t)r0 * N + (size_t)c4 * 4;
    float4 acc = make_float4(0.f, 0.f, 0.f, 0.f);
#pragma unroll 16
    for (int r = 0; r < 32; ++r) {
        float4 v = *(const float4*)(p + (size_t)r * N);
        acc.x += v.x; acc.y += v.y; acc.z += v.z; acc.w += v.w;
    }
    *(float4*)(partial + (size_t)blockIdx.y * N + (size_t)c4 * 4) = acc;
}

// ---------------------------------------------------------------------------
// Kernel 2: build aj[N][8] (blocks 0-15) and TRANSPOSED bkT[8][N] (blocks
// 16-31). bkT stores are coalesced per k (n consecutive across threads).
//   aj[n][k]  = b1[k] + sum_f E[n][f] * W1[k][f]
//   bkT[k][n] = sum_w[n] * W1[k][128] + sum_f E[n][f] * W1[k][64+f]
// ---------------------------------------------------------------------------
__global__ __launch_bounds__(256) void build_ajbk(const float* __restrict__ A,
                                                  const float* __restrict__ emb,
                                                  const float* __restrict__ W1,
                                                  const float* __restrict__ b1,
                                                  const float* __restrict__ partial,
                                                  float* __restrict__ aj,
                                                  float* __restrict__ bkT) {
    int b = blockIdx.x;
    int n = (b & 15) * 256 + threadIdx.x;

    float e[F];
#pragma unroll
    for (int f = 0; f < F; ++f) e[f] = emb[(size_t)f * N + n];

    if (b < 16) {
#pragma unroll
        for (int k = 0; k < H; ++k) {
            float a = b1[k];
#pragma unroll
            for (int f = 0; f < F; ++f) a += e[f] * W1[k * W1S + f];
            aj[n * H + k] = a;
        }
    } else {
        float s = 0.f;
#pragma unroll 32
        for (int p = 0; p < PCH; ++p) s += partial[(size_t)p * N + n];
        float sw = (s - A[(size_t)n * N + n]) * (1.0f / (float)(N - 1));
#pragma unroll
        for (int k = 0; k < H; ++k) {
            float v = sw * W1[k * W1S + 2 * F];
#pragma unroll
            for (int f = 0; f < F; ++f) v += e[f] * W1[k * W1S + F + f];
            bkT[(size_t)k * N + n] = v;
        }
    }
}

// ---------------------------------------------------------------------------
// Kernel 3: pure streaming fuse. Tile 32 rows x 256 cols, grid (16,128) =
// 2048 blocks (8/CU -> 8 waves/SIMD). No LDS, no syncthreads.
//   tx = t&63 -> 4 cols: bkT[k][j..j+3] loads are 1KB/wave contiguous.
//   ty = t>>6 (wave-uniform, readfirstlane-pinned) -> 8 rows; aj row loads
//   are wave-broadcast. Non-temporal 16B stores, 1KB/wave contiguous.
// ---------------------------------------------------------------------------
__global__ __launch_bounds__(256) void fuse_out(const float* __restrict__ aj,
                                                const float* __restrict__ bkT,
                                                const float* __restrict__ W2,
                                                const float* __restrict__ b2,
                                                float* __restrict__ out) {
    const int t  = threadIdx.x;
    const int tx = t & 63;
    const int ty = __builtin_amdgcn_readfirstlane(t >> 6);
    const int j  = blockIdx.x * 256 + tx * 4;
    const int i0 = blockIdx.y * 32 + ty * 8;

    f4 bk4[H];
#pragma unroll
    for (int k = 0; k < H; ++k) bk4[k] = *(const f4*)(bkT + (size_t)k * N + j);

    float w2[H];
#pragma unroll
    for (int k = 0; k < H; ++k) w2[k] = W2[k];   // W2[0][k]
    const float b20 = b2[0];

#pragma unroll
    for (int r = 0; r < 8; ++r) {
        int i = i0 + r;
        f4 alo = *(const f4*)(aj + (size_t)i * H);      // wave-uniform addr
        f4 ahi = *(const f4*)(aj + (size_t)i * H + 4);
        float a[H] = {alo.x, alo.y, alo.z, alo.w, ahi.x, ahi.y, ahi.z, ahi.w};

        f4 res = {b20, b20, b20, b20};
#pragma unroll
        for (int k = 0; k < H; ++k) {
            f4 tt = bk4[k];
            tt.x = fmaxf(a[k] + tt.x, 0.f);
            tt.y = fmaxf(a[k] + tt.y, 0.f);
            tt.z = fmaxf(a[k] + tt.z, 0.f);
            tt.w = fmaxf(a[k] + tt.w, 0.f);
            res.x += tt.x * w2[k];
            res.y += tt.y * w2[k];
            res.z += tt.z * w2[k];
            res.w += tt.w * w2[k];
        }
        __builtin_nontemporal_store(res, (f4*)(out + (size_t)i * N + j));
    }
}

extern "C" void kernel_launch(void* const* d_in, const int* in_sizes, int n_in,
                              void* d_out, int out_size, void* d_ws, size_t ws_size,
                              hipStream_t stream) {
    const float* adj = (const float*)d_in[0];   // (1, N, N)
    const float* emb = (const float*)d_in[1];   // (1, F, N)
    const float* W1  = (const float*)d_in[2];   // (H, 2F+1)
    const float* b1  = (const float*)d_in[3];   // (H,)
    const float* W2  = (const float*)d_in[4];   // (8, H)
    const float* b2  = (const float*)d_in[5];   // (8,)
    float* out = (float*)d_out;

    float* partial = (float*)d_ws;              // PCH * N floats = 2 MB
    float* aj  = partial + (size_t)PCH * N;     // N*H floats = 128 KB
    float* bkT = aj + (size_t)N * H;            // H*N floats = 128 KB

    colsum_partial<<<dim3(4, PCH), 256, 0, stream>>>(adj, partial);
    build_ajbk<<<dim3(32), 256, 0, stream>>>(adj, emb, W1, b1, partial, aj, bkT);
    fuse_out<<<dim3(N / 256, N / 32), 256, 0, stream>>>(aj, bkT, W2, b2, out);
}

// Round 12
// 50.623 us; speedup vs baseline: 1.3541x; 1.3541x over previous
//
#include <hip/hip_runtime.h>

#define N 4096
#define F 64
#define H 8
#define W1S (2 * F + 1)   // 129

typedef float f4 __attribute__((ext_vector_type(4)));

// ---------------------------------------------------------------------------
// K1 "prep": 544 blocks x 256.
//  blocks 0-511: column sums of A, atomicAdd into colsum[4096].
//    block b: cols (b&3)*1024 + t*4, rows (b>>2)*32 .. +31. float4, unrolled.
//  blocks 512-527: aj[n][8]  = b1 + E.W1a      (n = chunk*256+t, streaming)
//  blocks 528-543: bkF_T[k][n] = sum_f E.W1b   (coalesced per-k stores)
//  No e[] register array: e consumed as loaded (low VGPR, loads pipeline).
// ---------------------------------------------------------------------------
__global__ __launch_bounds__(256) void prep(const float* __restrict__ A,
                                            const float* __restrict__ emb,
                                            const float* __restrict__ W1,
                                            const float* __restrict__ b1,
                                            float* __restrict__ colsum,
                                            float* __restrict__ aj,
                                            float* __restrict__ bkF) {
    const int b = blockIdx.x;
    const int t = threadIdx.x;

    if (b < 512) {
        int c = (b & 3) * 1024 + t * 4;
        int r0 = (b >> 2) * 32;
        const float* p = A + (size_t)r0 * N + c;
        f4 acc = {0.f, 0.f, 0.f, 0.f};
#pragma unroll 16
        for (int r = 0; r < 32; ++r) {
            f4 v = *(const f4*)(p + (size_t)r * N);
            acc.x += v.x; acc.y += v.y; acc.z += v.z; acc.w += v.w;
        }
        atomicAdd(&colsum[c + 0], acc.x);
        atomicAdd(&colsum[c + 1], acc.y);
        atomicAdd(&colsum[c + 2], acc.z);
        atomicAdd(&colsum[c + 3], acc.w);
    } else {
        int idx = b - 512;                 // 0..31
        int n = (idx & 15) * 256 + t;
        if (idx < 16) {
            float av[H];
#pragma unroll
            for (int k = 0; k < H; ++k) av[k] = b1[k];
#pragma unroll
            for (int f = 0; f < F; ++f) {
                float e = emb[(size_t)f * N + n];
#pragma unroll
                for (int k = 0; k < H; ++k) av[k] += e * W1[k * W1S + f];
            }
#pragma unroll
            for (int k = 0; k < H; ++k) aj[n * H + k] = av[k];
        } else {
            float bv[H];
#pragma unroll
            for (int k = 0; k < H; ++k) bv[k] = 0.f;
#pragma unroll
            for (int f = 0; f < F; ++f) {
                float e = emb[(size_t)f * N + n];
#pragma unroll
                for (int k = 0; k < H; ++k) bv[k] += e * W1[k * W1S + F + f];
            }
#pragma unroll
            for (int k = 0; k < H; ++k) bkF[(size_t)k * N + n] = bv[k];
        }
    }
}

// ---------------------------------------------------------------------------
// K2 "fuse": grid (16,128) = 2048 blocks (8/CU), tile 256 cols x 32 rows.
// Phase A: thread t -> col j=j0+t: sw = (colsum[j]-A[j][j])/4095;
//          bks[k][t] = bkF_T[k][j] + sw*W1[k][128]  (LDS [8][260], 16B rows)
// Phase B: tx=t&63 -> 4 cols (bk4 regs from LDS), ty=t>>6 -> 8 rows;
//          aj loads wave-uniform broadcast; NT float4 stores 1KB/wave.
// ---------------------------------------------------------------------------
__global__ __launch_bounds__(256, 8) void fuse(const float* __restrict__ A,
                                               const float* __restrict__ W1,
                                               const float* __restrict__ aj,
                                               const float* __restrict__ bkF,
                                               const float* __restrict__ colsum,
                                               const float* __restrict__ W2,
                                               const float* __restrict__ b2,
                                               float* __restrict__ out) {
    __shared__ float bks[H][260];          // 1040B row stride: 16B-aligned, staggered banks

    const int t  = threadIdx.x;
    const int j0 = blockIdx.x * 256;
    const int i0 = blockIdx.y * 32;

    {
        int j = j0 + t;
        float sw = (colsum[j] - A[(size_t)j * N + j]) * (1.0f / (float)(N - 1));
#pragma unroll
        for (int k = 0; k < H; ++k)
            bks[k][t] = bkF[(size_t)k * N + j] + sw * W1[k * W1S + 2 * F];
    }
    __syncthreads();

    const int tx = t & 63;
    const int ty = __builtin_amdgcn_readfirstlane(t >> 6);

    f4 bk4[H];
#pragma unroll
    for (int k = 0; k < H; ++k) bk4[k] = *(const f4*)&bks[k][tx * 4];

    float w2[H];
#pragma unroll
    for (int k = 0; k < H; ++k) w2[k] = W2[k];   // W2[0][k]
    const float b20 = b2[0];

    const int j = j0 + tx * 4;
#pragma unroll
    for (int r = 0; r < 8; ++r) {
        int i = i0 + ty * 8 + r;
        f4 alo = *(const f4*)(aj + (size_t)i * H);      // wave-uniform addr
        f4 ahi = *(const f4*)(aj + (size_t)i * H + 4);
        float a[H] = {alo.x, alo.y, alo.z, alo.w, ahi.x, ahi.y, ahi.z, ahi.w};

        f4 res = {b20, b20, b20, b20};
#pragma unroll
        for (int k = 0; k < H; ++k) {
            f4 tt = bk4[k];
            tt.x = fmaxf(a[k] + tt.x, 0.f);
            tt.y = fmaxf(a[k] + tt.y, 0.f);
            tt.z = fmaxf(a[k] + tt.z, 0.f);
            tt.w = fmaxf(a[k] + tt.w, 0.f);
            res.x += tt.x * w2[k];
            res.y += tt.y * w2[k];
            res.z += tt.z * w2[k];
            res.w += tt.w * w2[k];
        }
        __builtin_nontemporal_store(res, (f4*)(out + (size_t)i * N + j));
    }
}

extern "C" void kernel_launch(void* const* d_in, const int* in_sizes, int n_in,
                              void* d_out, int out_size, void* d_ws, size_t ws_size,
                              hipStream_t stream) {
    const float* adj = (const float*)d_in[0];   // (1, N, N)
    const float* emb = (const float*)d_in[1];   // (1, F, N)
    const float* W1  = (const float*)d_in[2];   // (H, 2F+1)
    const float* b1  = (const float*)d_in[3];   // (H,)
    const float* W2  = (const float*)d_in[4];   // (8, H)
    const float* b2  = (const float*)d_in[5];   // (8,)
    float* out = (float*)d_out;

    float* colsum = (float*)d_ws;               // 4096 floats = 16 KB
    float* aj  = colsum + N;                    // N*H floats = 128 KB
    float* bkF = aj + (size_t)N * H;            // H*N floats = 128 KB

    hipMemsetAsync(colsum, 0, N * sizeof(float), stream);
    prep<<<dim3(544), 256, 0, stream>>>(adj, emb, W1, b1, colsum, aj, bkF);
    fuse<<<dim3(N / 256, N / 32), 256, 0, stream>>>(adj, W1, aj, bkF, colsum,
                                                    W2, b2, out);
}

// Round 13
// 39.801 us; speedup vs baseline: 1.7222x; 1.2719x over previous
//
#include <hip/hip_runtime.h>

#define N 4096
#define F 64
#define H 8
#define W1S (2 * F + 1)   // 129
#define PCH 128           // partial chunks (32 rows each)

typedef float f4 __attribute__((ext_vector_type(4)));

// ---------------------------------------------------------------------------
// K1 "prep": 544 blocks x 256. No atomics, no memset needed.
//  blocks 0-511: column sums of A (32-row chunks) -> partial[128][4096].
//  blocks 512-527: aj[n][8]  = b1 + E.W1a           (running accum, low VGPR)
//  blocks 528-543: bkF_T[k][n] = sum_f E.W1b        (coalesced per-k stores)
//                  + diag[n] = A[n][n]              (strided, tiny, hidden)
// ---------------------------------------------------------------------------
__global__ __launch_bounds__(256) void prep(const float* __restrict__ A,
                                            const float* __restrict__ emb,
                                            const float* __restrict__ W1,
                                            const float* __restrict__ b1,
                                            float* __restrict__ partial,
                                            float* __restrict__ aj,
                                            float* __restrict__ bkF,
                                            float* __restrict__ diag) {
    const int b = blockIdx.x;
    const int t = threadIdx.x;

    if (b < 512) {
        int c = (b & 3) * 1024 + t * 4;
        int r0 = (b >> 2) * 32;
        const float* p = A + (size_t)r0 * N + c;
        f4 acc = {0.f, 0.f, 0.f, 0.f};
#pragma unroll 16
        for (int r = 0; r < 32; ++r) {
            f4 v = *(const f4*)(p + (size_t)r * N);
            acc.x += v.x; acc.y += v.y; acc.z += v.z; acc.w += v.w;
        }
        *(f4*)(partial + (size_t)(b >> 2) * N + c) = acc;
    } else {
        int idx = b - 512;                 // 0..31
        int n = (idx & 15) * 256 + t;
        if (idx < 16) {
            float av[H];
#pragma unroll
            for (int k = 0; k < H; ++k) av[k] = b1[k];
#pragma unroll
            for (int f = 0; f < F; ++f) {
                float e = emb[(size_t)f * N + n];
#pragma unroll
                for (int k = 0; k < H; ++k) av[k] += e * W1[k * W1S + f];
            }
#pragma unroll
            for (int k = 0; k < H; ++k) aj[n * H + k] = av[k];
        } else {
            float bv[H];
#pragma unroll
            for (int k = 0; k < H; ++k) bv[k] = 0.f;
#pragma unroll
            for (int f = 0; f < F; ++f) {
                float e = emb[(size_t)f * N + n];
#pragma unroll
                for (int k = 0; k < H; ++k) bv[k] += e * W1[k * W1S + F + f];
            }
#pragma unroll
            for (int k = 0; k < H; ++k) bkF[(size_t)k * N + n] = bv[k];
            diag[n] = A[(size_t)n * N + n];
        }
    }
}

// ---------------------------------------------------------------------------
// K2 "fuse": grid (16,128) = 2048 blocks (8/CU), tile 256 cols x 32 rows.
// Phase A: thread t -> col j=j0+t: s = sum_{ch<128} partial[ch][j] (pipelined
//          independent loads, L2-resident); sw = (s - diag[j])/4095;
//          bks[k][t] = bkF_T[k][j] + sw*W1[k][128]   (LDS [8][260])
// Phase B: tx=t&63 -> 4 cols (bk4 regs), ty=t>>6 -> 8 rows; aj loads
//          wave-uniform broadcast; float4 stores 1KB/wave contiguous.
// ---------------------------------------------------------------------------
__global__ __launch_bounds__(256, 8) void fuse(const float* __restrict__ W1,
                                               const float* __restrict__ aj,
                                               const float* __restrict__ bkF,
                                               const float* __restrict__ partial,
                                               const float* __restrict__ diag,
                                               const float* __restrict__ W2,
                                               const float* __restrict__ b2,
                                               float* __restrict__ out) {
    __shared__ float bks[H][260];          // 1040B row stride, 16B-aligned

    const int t  = threadIdx.x;
    const int j0 = blockIdx.x * 256;
    const int i0 = blockIdx.y * 32;

    {
        int j = j0 + t;
        float s = 0.f;
        const float* pp = partial + j;
#pragma unroll 16
        for (int ch = 0; ch < PCH; ++ch) s += pp[(size_t)ch * N];
        float sw = (s - diag[j]) * (1.0f / (float)(N - 1));
#pragma unroll
        for (int k = 0; k < H; ++k)
            bks[k][t] = bkF[(size_t)k * N + j] + sw * W1[k * W1S + 2 * F];
    }
    __syncthreads();

    const int tx = t & 63;
    const int ty = __builtin_amdgcn_readfirstlane(t >> 6);

    f4 bk4[H];
#pragma unroll
    for (int k = 0; k < H; ++k) bk4[k] = *(const f4*)&bks[k][tx * 4];

    float w2[H];
#pragma unroll
    for (int k = 0; k < H; ++k) w2[k] = W2[k];   // W2[0][k]
    const float b20 = b2[0];

    const int j = j0 + tx * 4;
#pragma unroll
    for (int r = 0; r < 8; ++r) {
        int i = i0 + ty * 8 + r;
        f4 alo = *(const f4*)(aj + (size_t)i * H);      // wave-uniform addr
        f4 ahi = *(const f4*)(aj + (size_t)i * H + 4);
        float a[H] = {alo.x, alo.y, alo.z, alo.w, ahi.x, ahi.y, ahi.z, ahi.w};

        f4 res = {b20, b20, b20, b20};
#pragma unroll
        for (int k = 0; k < H; ++k) {
            f4 tt = bk4[k];
            tt.x = fmaxf(a[k] + tt.x, 0.f);
            tt.y = fmaxf(a[k] + tt.y, 0.f);
            tt.z = fmaxf(a[k] + tt.z, 0.f);
            tt.w = fmaxf(a[k] + tt.w, 0.f);
            res.x += tt.x * w2[k];
            res.y += tt.y * w2[k];
            res.z += tt.z * w2[k];
            res.w += tt.w * w2[k];
        }
        *(f4*)(out + (size_t)i * N + j) = res;
    }
}

extern "C" void kernel_launch(void* const* d_in, const int* in_sizes, int n_in,
                              void* d_out, int out_size, void* d_ws, size_t ws_size,
                              hipStream_t stream) {
    const float* adj = (const float*)d_in[0];   // (1, N, N)
    const float* emb = (const float*)d_in[1];   // (1, F, N)
    const float* W1  = (const float*)d_in[2];   // (H, 2F+1)
    const float* b1  = (const float*)d_in[3];   // (H,)
    const float* W2  = (const float*)d_in[4];   // (8, H)
    const float* b2  = (const float*)d_in[5];   // (8,)
    float* out = (float*)d_out;

    float* partial = (float*)d_ws;              // 128*4096 floats = 2 MB
    float* aj   = partial + (size_t)PCH * N;    // N*H floats = 128 KB
    float* bkF  = aj + (size_t)N * H;           // H*N floats = 128 KB
    float* diag = bkF + (size_t)H * N;          // N floats = 16 KB

    prep<<<dim3(544), 256, 0, stream>>>(adj, emb, W1, b1, partial, aj, bkF, diag);
    fuse<<<dim3(N / 256, N / 32), 256, 0, stream>>>(W1, aj, bkF, partial, diag,
                                                    W2, b2, out);
}

// Round 14
// 39.388 us; speedup vs baseline: 1.7403x; 1.0105x over previous
//
#include <hip/hip_runtime.h>

#define N 4096
#define F 64
#define H 8
#define W1S (2 * F + 1)   // 129
#define PCH 32            // partial chunks (128 rows each)

typedef float f4 __attribute__((ext_vector_type(4)));

// ---------------------------------------------------------------------------
// K1 "prep": 544 blocks x 256. No atomics, no memset.
//  blocks 0-511: column sums of A -> partial[32][4096].
//    block b: stripe s=b&15 (256 cols), chunk ch=b>>4 (128 rows).
//    thread t -> col j=s*256+t, scalar loads (wave reads 256B contiguous,
//    4 waves cover 1KB), 128 independent loads pipelined.
//  blocks 512-527: aj[n][8]  = b1 + E.W1a          (running accum, low VGPR)
//  blocks 528-543: bkF_T[k][n] = sum_f E.W1b       (coalesced per-k stores)
//                  + diag[n] = A[n][n]
// ---------------------------------------------------------------------------
__global__ __launch_bounds__(256) void prep(const float* __restrict__ A,
                                            const float* __restrict__ emb,
                                            const float* __restrict__ W1,
                                            const float* __restrict__ b1,
                                            float* __restrict__ partial,
                                            float* __restrict__ aj,
                                            float* __restrict__ bkF,
                                            float* __restrict__ diag) {
    const int b = blockIdx.x;
    const int t = threadIdx.x;

    if (b < 512) {
        int s  = b & 15;
        int ch = b >> 4;
        int j  = s * 256 + t;
        const float* p = A + (size_t)(ch * 128) * N + j;
        float s0 = 0.f, s1 = 0.f, s2 = 0.f, s3 = 0.f;
#pragma unroll 8
        for (int r = 0; r < 128; r += 4) {
            s0 += p[(size_t)(r + 0) * N];
            s1 += p[(size_t)(r + 1) * N];
            s2 += p[(size_t)(r + 2) * N];
            s3 += p[(size_t)(r + 3) * N];
        }
        partial[(size_t)ch * N + j] = (s0 + s1) + (s2 + s3);
    } else {
        int idx = b - 512;                 // 0..31
        int n = (idx & 15) * 256 + t;
        if (idx < 16) {
            float av[H];
#pragma unroll
            for (int k = 0; k < H; ++k) av[k] = b1[k];
#pragma unroll
            for (int f = 0; f < F; ++f) {
                float e = emb[(size_t)f * N + n];
#pragma unroll
                for (int k = 0; k < H; ++k) av[k] += e * W1[k * W1S + f];
            }
#pragma unroll
            for (int k = 0; k < H; ++k) aj[n * H + k] = av[k];
        } else {
            float bv[H];
#pragma unroll
            for (int k = 0; k < H; ++k) bv[k] = 0.f;
#pragma unroll
            for (int f = 0; f < F; ++f) {
                float e = emb[(size_t)f * N + n];
#pragma unroll
                for (int k = 0; k < H; ++k) bv[k] += e * W1[k * W1S + F + f];
            }
#pragma unroll
            for (int k = 0; k < H; ++k) bkF[(size_t)k * N + n] = bv[k];
            diag[n] = A[(size_t)n * N + n];
        }
    }
}

// ---------------------------------------------------------------------------
// K2 "fuse": grid (16,64) = 1024 blocks (4/CU), tile 256 cols x 64 rows.
// Phase A: thread t -> col j=j0+t: s = sum_{ch<32} partial[ch][j] (pipelined,
//          33 MB aggregate); sw = (s - diag[j])/4095;
//          bks[k][t] = bkF_T[k][j] + sw*W1[k][128]   (LDS [8][260])
// Phase B: tx=t&63 -> 4 cols (bk4 regs), ty=t>>6 -> 16 rows; aj loads
//          wave-uniform broadcast; float4 stores 1KB/wave contiguous.
// ---------------------------------------------------------------------------
__global__ __launch_bounds__(256, 8) void fuse(const float* __restrict__ W1,
                                               const float* __restrict__ aj,
                                               const float* __restrict__ bkF,
                                               const float* __restrict__ partial,
                                               const float* __restrict__ diag,
                                               const float* __restrict__ W2,
                                               const float* __restrict__ b2,
                                               float* __restrict__ out) {
    __shared__ float bks[H][260];          // 1040B row stride, 16B-aligned

    const int t  = threadIdx.x;
    const int j0 = blockIdx.x * 256;
    const int i0 = blockIdx.y * 64;

    {
        int j = j0 + t;
        float s = 0.f;
        const float* pp = partial + j;
#pragma unroll
        for (int ch = 0; ch < PCH; ++ch) s += pp[(size_t)ch * N];
        float sw = (s - diag[j]) * (1.0f / (float)(N - 1));
#pragma unroll
        for (int k = 0; k < H; ++k)
            bks[k][t] = bkF[(size_t)k * N + j] + sw * W1[k * W1S + 2 * F];
    }
    __syncthreads();

    const int tx = t & 63;
    const int ty = __builtin_amdgcn_readfirstlane(t >> 6);

    f4 bk4[H];
#pragma unroll
    for (int k = 0; k < H; ++k) bk4[k] = *(const f4*)&bks[k][tx * 4];

    float w2[H];
#pragma unroll
    for (int k = 0; k < H; ++k) w2[k] = W2[k];   // W2[0][k]
    const float b20 = b2[0];

    const int j = j0 + tx * 4;
#pragma unroll
    for (int r = 0; r < 16; ++r) {
        int i = i0 + ty * 16 + r;
        f4 alo = *(const f4*)(aj + (size_t)i * H);      // wave-uniform addr
        f4 ahi = *(const f4*)(aj + (size_t)i * H + 4);
        float a[H] = {alo.x, alo.y, alo.z, alo.w, ahi.x, ahi.y, ahi.z, ahi.w};

        f4 res = {b20, b20, b20, b20};
#pragma unroll
        for (int k = 0; k < H; ++k) {
            f4 tt = bk4[k];
            tt.x = fmaxf(a[k] + tt.x, 0.f);
            tt.y = fmaxf(a[k] + tt.y, 0.f);
            tt.z = fmaxf(a[k] + tt.z, 0.f);
            tt.w = fmaxf(a[k] + tt.w, 0.f);
            res.x += tt.x * w2[k];
            res.y += tt.y * w2[k];
            res.z += tt.z * w2[k];
            res.w += tt.w * w2[k];
        }
        *(f4*)(out + (size_t)i * N + j) = res;
    }
}

extern "C" void kernel_launch(void* const* d_in, const int* in_sizes, int n_in,
                              void* d_out, int out_size, void* d_ws, size_t ws_size,
                              hipStream_t stream) {
    const float* adj = (const float*)d_in[0];   // (1, N, N)
    const float* emb = (const float*)d_in[1];   // (1, F, N)
    const float* W1  = (const float*)d_in[2];   // (H, 2F+1)
    const float* b1  = (const float*)d_in[3];   // (H,)
    const float* W2  = (const float*)d_in[4];   // (8, H)
    const float* b2  = (const float*)d_in[5];   // (8,)
    float* out = (float*)d_out;

    float* partial = (float*)d_ws;              // 32*4096 floats = 512 KB
    float* aj   = partial + (size_t)PCH * N;    // N*H floats = 128 KB
    float* bkF  = aj + (size_t)N * H;           // H*N floats = 128 KB
    float* diag = bkF + (size_t)H * N;          // N floats = 16 KB

    prep<<<dim3(544), 256, 0, stream>>>(adj, emb, W1, b1, partial, aj, bkF, diag);
    fuse<<<dim3(N / 256, N / 64), 256, 0, stream>>>(W1, aj, bkF, partial, diag,
                                                    W2, b2, out);
}